// Round 2
// baseline (1532.017 us; speedup 1.0000x reference)
//
#include <hip/hip_runtime.h>
#include <hip/hip_bf16.h>
#include <math.h>

typedef __attribute__((ext_vector_type(8))) short bf16x8;
typedef __attribute__((ext_vector_type(4))) float f32x4;
typedef __attribute__((ext_vector_type(4))) float f4;
typedef __attribute__((ext_vector_type(8))) unsigned short us8;
typedef unsigned short u16;
typedef unsigned int u32;

#define HEADS 8
#define SHIFT_ 3
#define HIMG 56
#define WIMG 56
#define WA 49
#define NTOK 100352   // 32*56*56
#define NPAIR 16384   // 2048 windows * 8 heads

static __device__ __forceinline__ float bf2f(u16 v){ return __uint_as_float(((u32)v)<<16); }
static __device__ __forceinline__ u16 f2bf(float f){
  u32 u = __float_as_uint(f);
  return (u16)((u + 0x7fffu + ((u>>16)&1u)) >> 16);
}
static __device__ __forceinline__ float wsum(float v){
  #pragma unroll
  for (int off=32; off>0; off>>=1) v += __shfl_xor(v, off, 64);
  return v;
}
// token index (window order, shifted) -> pixel index (raster order). Same map
// forward (gather for QKV) and reverse (scatter for proj epilogue).
static __device__ __forceinline__ int tok2pix(int row){
  int bw = row / 49, t = row - bw*49;
  int b  = bw >> 6,  w = bw & 63;
  int wh = w >> 3,   ww = w & 7;
  int th = t / 7,    tw = t - th*7;
  int r = wh*7 + th + SHIFT_; if (r >= HIMG) r -= HIMG;
  int c = ww*7 + tw + SHIFT_; if (c >= WIMG) c -= WIMG;
  return (b*HIMG + r)*WIMG + c;
}

// ---------------- per-token LayerNorm stats (mean, rstd) ----------------
// ISBF: 0 = f32 source, 1 = bf16 source
template<int C, int ISBF>
__global__ void ln_stats_kernel(const void* __restrict__ srcv, float* __restrict__ stats){
  int wave = threadIdx.x >> 6, lane = threadIdx.x & 63;
  int tok = blockIdx.x*4 + wave;
  float s=0.f, s2=0.f;
  if (ISBF == 0){
    const float* p = (const float*)srcv + (size_t)tok*C;
    #pragma unroll
    for (int i=0;i<C/256;i++){
      f4 v = *(const f4*)(p + lane*4*(C/256) + i*4);
      #pragma unroll
      for (int e=0;e<4;e++){ float f=v[e]; s+=f; s2+=f*f; }
    }
  } else {
    const u16* p = (const u16*)srcv + (size_t)tok*C;
    #pragma unroll
    for (int i=0;i<C/512;i++){
      us8 v = *(const us8*)(p + lane*8*(C/512) + i*8);
      #pragma unroll
      for (int e=0;e<8;e++){ float f=bf2f(v[e]); s+=f; s2+=f*f; }
    }
  }
  s = wsum(s); s2 = wsum(s2);
  if (lane==0){
    float mean = s/(float)C;
    float var  = s2/(float)C - mean*mean;
    stats[2*tok]   = mean;
    stats[2*tok+1] = rsqrtf(var + 1e-5f);
  }
}

// ------------- fold LN affine into weights: W' = bf16(W*ln_w), b' = b + W@ln_b -------------
// Also converts proj_w to bf16 (no LN fold).
__global__ void prep_weights(
    const float* __restrict__ qkv_w, const float* __restrict__ qkv_b,
    const float* __restrict__ ln1w,  const float* __restrict__ ln1b,
    const float* __restrict__ fc1_w, const float* __restrict__ fc1_b,
    const float* __restrict__ ln2w,  const float* __restrict__ ln2b,
    const float* __restrict__ fc2_w, const float* __restrict__ fc2_b,
    const float* __restrict__ ln3w,  const float* __restrict__ ln3b,
    const float* __restrict__ proj_w, const float* __restrict__ proj_b,
    u16* __restrict__ wq, float* __restrict__ bq,
    u16* __restrict__ w1, float* __restrict__ b1,
    u16* __restrict__ w2, float* __restrict__ b2,
    u16* __restrict__ wp, float* __restrict__ bp)
{
  int wave = threadIdx.x>>6, lane = threadIdx.x&63;
  int n = blockIdx.x*4 + wave;            // 0..2303
  const float *W,*lw,*lb,*bs; u16* WO; float* BO; int K, row, noln;
  if (n < 768)      { W=qkv_w; lw=ln1w; lb=ln1b; bs=qkv_b; WO=wq; BO=bq; K=256;  row=n;      noln=0; }
  else if (n < 1792){ W=fc1_w; lw=ln2w; lb=ln2b; bs=fc1_b; WO=w1; BO=b1; K=256;  row=n-768;  noln=0; }
  else if (n < 2048){ W=fc2_w; lw=ln3w; lb=ln3b; bs=fc2_b; WO=w2; BO=b2; K=1024; row=n-1792; noln=0; }
  else              { W=proj_w; lw=nullptr; lb=nullptr; bs=proj_b; WO=wp; BO=bp; K=256; row=n-2048; noln=1; }
  float dot = 0.f;
  for (int k=lane; k<K; k+=64){
    float wv = W[(size_t)row*K + k];
    if (noln){
      WO[(size_t)row*K + k] = f2bf(wv);
    } else {
      dot += wv * lb[k];
      WO[(size_t)row*K + k] = f2bf(wv * lw[k]);
    }
  }
  dot = wsum(dot);
  if (lane==0) BO[row] = bs[row] + dot;
}

// ---------------- GEMM: C = A' @ Bt^T (+bias, +epilogue) ----------------
// AMODE: 0 = gather rows via tok2pix + LN (QKV on x)
//        1 = plain rows, no LN (proj on attn_out)
//        2 = plain rows + LN (fc1 on x1, fc2 on h)
// ADT:   0 = A is f32, 1 = A is bf16
// EPI:   0 = +bias, split/store q|k|v bf16 as [which][pair][49][32]
//        1 = +bias + x residual (f32), scatter f32 to d_out via tok2pix
//        2 = +bias, exact GELU, store bf16 h [row][1024]
//        3 = +bias + out residual (f32), store f32 out [row][256]
template<int AMODE, int ADT, int EPI>
__global__ void gemm_kernel(
    const void* __restrict__ Av, const u16* __restrict__ Bt,
    const float* __restrict__ stats, const float* __restrict__ biasf,
    const float* __restrict__ resid, void* __restrict__ outv, int K, int NT)
{
  constexpr int BM=128, BN=128, BKt=64;
  __shared__ u16 As[BM*BKt];
  __shared__ u16 Bs[BN*BKt];
  int bid = blockIdx.x;
  int mt = bid / NT, nt = bid - mt*NT;
  int m0 = mt*BM, n0 = nt*BN;
  int tid  = threadIdx.x;
  int lane = tid & 63, wave = tid >> 6;
  int wr = wave >> 1, wc = wave & 1;

  f32x4 acc[4][4];
  #pragma unroll
  for (int i=0;i<4;i++)
    #pragma unroll
    for (int j=0;j<4;j++){ acc[i][j][0]=0.f; acc[i][j][1]=0.f; acc[i][j][2]=0.f; acc[i][j][3]=0.f; }

  for (int kt=0; kt<K; kt+=BKt){
    #pragma unroll
    for (int i=0;i<4;i++){                       // stage A (with optional LN), convert to bf16
      int c = tid + i*256;
      int row = c >> 3, k8 = (c & 7)*8;
      int grow = (AMODE==0) ? tok2pix(m0+row) : (m0+row);
      float fv[8];
      if (ADT == 0){
        const float* ap = (const float*)Av + (size_t)grow*K + kt + k8;
        f4 a0 = *(const f4*)ap, a1 = *(const f4*)(ap+4);
        #pragma unroll
        for (int e=0;e<4;e++){ fv[e]=a0[e]; fv[4+e]=a1[e]; }
      } else {
        us8 v = *(const us8*)((const u16*)Av + (size_t)grow*K + kt + k8);
        #pragma unroll
        for (int e=0;e<8;e++) fv[e] = bf2f(v[e]);
      }
      if (AMODE != 1){
        float mean = stats[2*grow], rstd = stats[2*grow+1];
        #pragma unroll
        for (int e=0;e<8;e++) fv[e] = (fv[e]-mean)*rstd;
      }
      us8 o;
      #pragma unroll
      for (int e=0;e<8;e++) o[e] = f2bf(fv[e]);
      *(us8*)(As + row*BKt + k8) = o;
    }
    #pragma unroll
    for (int i=0;i<4;i++){                       // stage B (prepped bf16)
      int c = tid + i*256;
      int row = c >> 3, k8 = (c & 7)*8;
      *(us8*)(Bs + row*BKt + k8) = *(const us8*)(Bt + (size_t)(n0+row)*K + kt + k8);
    }
    __syncthreads();
    #pragma unroll
    for (int kk=0; kk<2; kk++){
      bf16x8 af[4], bfr[4];
      #pragma unroll
      for (int mi=0;mi<4;mi++){
        int r = wr*64 + mi*16 + (lane & 15);
        af[mi] = *(const bf16x8*)(As + r*BKt + kk*32 + (lane>>4)*8);
      }
      #pragma unroll
      for (int ni=0;ni<4;ni++){
        int r = wc*64 + ni*16 + (lane & 15);
        bfr[ni] = *(const bf16x8*)(Bs + r*BKt + kk*32 + (lane>>4)*8);
      }
      #pragma unroll
      for (int mi=0;mi<4;mi++)
        #pragma unroll
        for (int ni=0;ni<4;ni++)
          acc[mi][ni] = __builtin_amdgcn_mfma_f32_16x16x32_bf16(af[mi], bfr[ni], acc[mi][ni], 0, 0, 0);
    }
    __syncthreads();
  }

  int lr = lane >> 4, lc = lane & 15;
  #pragma unroll
  for (int mi=0;mi<4;mi++){
    #pragma unroll
    for (int ni=0;ni<4;ni++){
      int col = n0 + wc*64 + ni*16 + lc;
      #pragma unroll
      for (int j=0;j<4;j++){
        int row = m0 + wr*64 + mi*16 + lr*4 + j;
        float v = acc[mi][ni][j] + biasf[col];
        if (EPI==0){
          int which = col >> 8, hh = (col >> 5) & 7, d = col & 31;
          int bw = row / 49, t = row - bw*49;
          size_t dst = ((size_t)which*NPAIR + (size_t)bw*HEADS + hh)*(WA*32) + (size_t)t*32 + d;
          ((u16*)outv)[dst] = f2bf(v);
        } else if (EPI==1){
          int pix = tok2pix(row);
          v += resid[(size_t)pix*256 + col];
          ((float*)outv)[(size_t)pix*256 + col] = v;
        } else if (EPI==2){
          v = 0.5f*v*(1.f + erff(v*0.70710678118654752f));
          ((u16*)outv)[(size_t)row*1024 + col] = f2bf(v);
        } else {
          v += resid[(size_t)row*256 + col];
          ((float*)outv)[(size_t)row*256 + col] = v;
        }
      }
    }
  }
}

// ---------------- windowed attention: one wave per (window, head) ----------------
__global__ void attn_kernel(
    const u16* __restrict__ qkv,    // [3][NPAIR][49][32] bf16
    const float* __restrict__ rpb,  // [169][8] f32
    const int* __restrict__ rel,    // [49][49]
    const float* __restrict__ mask, // [64][49][49] f32
    u16* __restrict__ outb)         // [NTOK][256] bf16 (window-token order)
{
  int wave = threadIdx.x>>6, lane = threadIdx.x&63;
  int pair = blockIdx.x*4 + wave;
  int bw = pair >> 3, h = pair & 7;
  int w = bw & 63;
  __shared__ u16 kls[4][WA*32];
  __shared__ u16 vls[4][WA*32];
  const u16* kg = qkv + ((size_t)NPAIR   + pair)*(WA*32);
  const u16* vg = qkv + ((size_t)2*NPAIR + pair)*(WA*32);
  #pragma unroll
  for (int i=0;i<4;i++){
    int idx = i*64 + lane;
    if (idx < 196){
      *(us8*)(&kls[wave][idx*8]) = *(const us8*)(kg + idx*8);
      *(us8*)(&vls[wave][idx*8]) = *(const us8*)(vg + idx*8);
    }
  }
  float q[32];
  int t = lane;
  const u16* qg = qkv + (size_t)pair*(WA*32) + t*32;
  if (t < WA){
    #pragma unroll
    for (int i=0;i<4;i++){
      us8 v = *(const us8*)(qg + i*8);
      #pragma unroll
      for (int e=0;e<8;e++) q[i*8+e] = bf2f(v[e]) * 0.17677669529663689f; // 1/sqrt(32)
    }
  }
  __syncthreads();
  if (t < WA){
    float s[WA];
    const int* relrow = rel + t*WA;
    const float* maskrow = mask + ((size_t)w*WA + t)*WA;
    #pragma unroll
    for (int j=0;j<WA;j++){
      float d = 0.f;
      #pragma unroll
      for (int i=0;i<4;i++){
        us8 kv = *(const us8*)(&kls[wave][j*32 + i*8]);
        #pragma unroll
        for (int e=0;e<8;e++) d += q[i*8+e]*bf2f(kv[e]);
      }
      d += rpb[relrow[j]*8 + h];
      d += maskrow[j];
      s[j] = d;
    }
    float mx = s[0];
    #pragma unroll
    for (int j=1;j<WA;j++) mx = fmaxf(mx, s[j]);
    float sum = 0.f;
    #pragma unroll
    for (int j=0;j<WA;j++){ s[j] = __expf(s[j]-mx); sum += s[j]; }
    float rinv = 1.f/sum;
    float o[32];
    #pragma unroll
    for (int e=0;e<32;e++) o[e]=0.f;
    #pragma unroll
    for (int j=0;j<WA;j++){
      float p = s[j];
      #pragma unroll
      for (int i=0;i<4;i++){
        us8 vv = *(const us8*)(&vls[wave][j*32 + i*8]);
        #pragma unroll
        for (int e=0;e<8;e++) o[i*8+e] += p*bf2f(vv[e]);
      }
    }
    int row = bw*WA + t;
    u16* op = outb + (size_t)row*256 + h*32;
    #pragma unroll
    for (int e=0;e<32;e++) op[e] = f2bf(o[e]*rinv);
  }
}

extern "C" void kernel_launch(void* const* d_in, const int* in_sizes, int n_in,
                              void* d_out, int out_size, void* d_ws, size_t ws_size,
                              hipStream_t stream) {
  const float* x      = (const float*)d_in[0];
  const float* ln1w   = (const float*)d_in[1];
  const float* ln1b   = (const float*)d_in[2];
  const float* qkv_w  = (const float*)d_in[3];
  const float* qkv_b  = (const float*)d_in[4];
  const float* rpb    = (const float*)d_in[5];
  const float* proj_w = (const float*)d_in[6];
  const float* proj_b = (const float*)d_in[7];
  const float* ln2w   = (const float*)d_in[8];
  const float* ln2b   = (const float*)d_in[9];
  const float* fc1_w  = (const float*)d_in[10];
  const float* fc1_b  = (const float*)d_in[11];
  const float* ln3w   = (const float*)d_in[12];
  const float* ln3b   = (const float*)d_in[13];
  const float* fc2_w  = (const float*)d_in[14];
  const float* fc2_b  = (const float*)d_in[15];
  const float* amask  = (const float*)d_in[16];
  const int*   rel    = (const int*)d_in[17];
  float* out = (float*)d_out;

  char* ws = (char*)d_ws;
  float* statsA = (float*)(ws);                        // 100352*2*4 = 802816
  float* statsB = (float*)(ws +  802816);
  float* statsC = (float*)(ws + 1605632);
  float* bq     = (float*)(ws + 2408448);              // 768*4
  float* b1     = (float*)(ws + 2411520);              // 1024*4
  float* b2     = (float*)(ws + 2415616);              // 256*4
  float* bp     = (float*)(ws + 2416640);              // 256*4
  u16*   wq     = (u16*)  (ws + 2417664);              // 768*256*2  = 393216
  u16*   w1     = (u16*)  (ws + 2810880);              // 1024*256*2 = 524288
  u16*   w2     = (u16*)  (ws + 3335168);              // 256*1024*2 = 524288
  u16*   wp     = (u16*)  (ws + 3859456);              // 256*256*2  = 131072
  u16*   qkvbuf = (u16*)  (ws + 3990528);              // 3*NPAIR*49*32*2 = 154140672
  u16*   attno  = (u16*)  (ws + 3990528 + 154140672);  // NTOK*256*2 = 51380224
  u16*   hbuf   = (u16*)  (ws + 3990528);              // NTOK*1024*2 (aliases qkvbuf+attno)

  prep_weights<<<576,256,0,stream>>>(qkv_w,qkv_b,ln1w,ln1b, fc1_w,fc1_b,ln2w,ln2b,
                                     fc2_w,fc2_b,ln3w,ln3b, proj_w,proj_b,
                                     wq,bq, w1,b1, w2,b2, wp,bp);
  ln_stats_kernel<256,0><<<NTOK/4,256,0,stream>>>(x, statsA);
  // QKV: gather+LN f32 x @ wq' -> qkvbuf (bf16, split q|k|v)
  gemm_kernel<0,0,0><<<784*6,256,0,stream>>>(x, wq, statsA, bq, nullptr, qkvbuf, 256, 6);
  attn_kernel<<<NPAIR/4,256,0,stream>>>(qkvbuf, rpb, rel, amask, attno);
  // proj: attno(bf16) @ wp -> scatter f32 out = x + proj
  gemm_kernel<1,1,1><<<784*2,256,0,stream>>>(attno, wp, nullptr, bp, x, out, 256, 2);
  ln_stats_kernel<256,0><<<NTOK/4,256,0,stream>>>(out, statsB);
  // fc1: LN(out) @ w1' -> GELU -> hbuf (bf16)
  gemm_kernel<2,0,2><<<784*8,256,0,stream>>>(out, w1, statsB, b1, nullptr, hbuf, 256, 8);
  ln_stats_kernel<1024,1><<<NTOK/4,256,0,stream>>>(hbuf, statsC);
  // fc2: LN(hbuf bf16) @ w2' + out residual -> f32 out
  gemm_kernel<2,1,3><<<784*2,256,0,stream>>>(hbuf, w2, statsC, b2, out, out, 1024, 2);
}

// Round 3
// 886.010 us; speedup vs baseline: 1.7291x; 1.7291x over previous
//
#include <hip/hip_runtime.h>
#include <hip/hip_bf16.h>
#include <math.h>

typedef __attribute__((ext_vector_type(8))) short bf16x8;
typedef __attribute__((ext_vector_type(4))) float f32x4;
typedef __attribute__((ext_vector_type(4))) float f4;
typedef __attribute__((ext_vector_type(8))) unsigned short us8;
typedef unsigned short u16;
typedef unsigned int u32;

#define HEADS 8
#define SHIFT_ 3
#define HIMG 56
#define WIMG 56
#define WA 49
#define NTOK 100352   // 32*56*56
#define NPAIR 16384   // 2048 windows * 8 heads

static __device__ __forceinline__ float bf2f(u16 v){ return __uint_as_float(((u32)v)<<16); }
static __device__ __forceinline__ u16 f2bf(float f){
  u32 u = __float_as_uint(f);
  return (u16)((u + 0x7fffu + ((u>>16)&1u)) >> 16);
}
static __device__ __forceinline__ float wsum(float v){
  #pragma unroll
  for (int off=32; off>0; off>>=1) v += __shfl_xor(v, off, 64);
  return v;
}
// token index (window order, shifted) -> pixel index (raster order).
static __device__ __forceinline__ int tok2pix(int row){
  int bw = row / 49, t = row - bw*49;
  int b  = bw >> 6,  w = bw & 63;
  int wh = w >> 3,   ww = w & 7;
  int th = t / 7,    tw = t - th*7;
  int r = wh*7 + th + SHIFT_; if (r >= HIMG) r -= HIMG;
  int c = ww*7 + tw + SHIFT_; if (c >= WIMG) c -= WIMG;
  return (b*HIMG + r)*WIMG + c;
}

// ---------------- per-token LayerNorm stats (mean, rstd) ----------------
template<int C, int ISBF>
__global__ void ln_stats_kernel(const void* __restrict__ srcv, float* __restrict__ stats){
  int wave = threadIdx.x >> 6, lane = threadIdx.x & 63;
  int tok = blockIdx.x*4 + wave;
  float s=0.f, s2=0.f;
  if (ISBF == 0){
    const float* p = (const float*)srcv + (size_t)tok*C;
    #pragma unroll
    for (int i=0;i<C/256;i++){
      f4 v = *(const f4*)(p + lane*4*(C/256) + i*4);
      #pragma unroll
      for (int e=0;e<4;e++){ float f=v[e]; s+=f; s2+=f*f; }
    }
  } else {
    const u16* p = (const u16*)srcv + (size_t)tok*C;
    #pragma unroll
    for (int i=0;i<C/512;i++){
      us8 v = *(const us8*)(p + lane*8*(C/512) + i*8);
      #pragma unroll
      for (int e=0;e<8;e++){ float f=bf2f(v[e]); s+=f; s2+=f*f; }
    }
  }
  s = wsum(s); s2 = wsum(s2);
  if (lane==0){
    float mean = s/(float)C;
    float var  = s2/(float)C - mean*mean;
    stats[2*tok]   = mean;
    stats[2*tok+1] = rsqrtf(var + 1e-5f);
  }
}

// ------------- fold LN affine into weights -------------
__global__ void prep_weights(
    const float* __restrict__ qkv_w, const float* __restrict__ qkv_b,
    const float* __restrict__ ln1w,  const float* __restrict__ ln1b,
    const float* __restrict__ fc1_w, const float* __restrict__ fc1_b,
    const float* __restrict__ ln2w,  const float* __restrict__ ln2b,
    const float* __restrict__ fc2_w, const float* __restrict__ fc2_b,
    const float* __restrict__ ln3w,  const float* __restrict__ ln3b,
    const float* __restrict__ proj_w, const float* __restrict__ proj_b,
    u16* __restrict__ wq, float* __restrict__ bq,
    u16* __restrict__ w1, float* __restrict__ b1,
    u16* __restrict__ w2, float* __restrict__ b2,
    u16* __restrict__ wp, float* __restrict__ bp)
{
  int wave = threadIdx.x>>6, lane = threadIdx.x&63;
  int n = blockIdx.x*4 + wave;            // 0..2303
  const float *W,*lw,*lb,*bs; u16* WO; float* BO; int K, row, noln;
  if (n < 768)      { W=qkv_w; lw=ln1w; lb=ln1b; bs=qkv_b; WO=wq; BO=bq; K=256;  row=n;      noln=0; }
  else if (n < 1792){ W=fc1_w; lw=ln2w; lb=ln2b; bs=fc1_b; WO=w1; BO=b1; K=256;  row=n-768;  noln=0; }
  else if (n < 2048){ W=fc2_w; lw=ln3w; lb=ln3b; bs=fc2_b; WO=w2; BO=b2; K=1024; row=n-1792; noln=0; }
  else              { W=proj_w; lw=nullptr; lb=nullptr; bs=proj_b; WO=wp; BO=bp; K=256; row=n-2048; noln=1; }
  float dot = 0.f;
  for (int k=lane; k<K; k+=64){
    float wv = W[(size_t)row*K + k];
    if (noln){
      WO[(size_t)row*K + k] = f2bf(wv);
    } else {
      dot += wv * lb[k];
      WO[(size_t)row*K + k] = f2bf(wv * lw[k]);
    }
  }
  dot = wsum(dot);
  if (lane==0) BO[row] = bs[row] + dot;
}

// ---------------- GEMM: C = A' @ Bt^T (+bias, +epilogue) ----------------
// AMODE: 0 = gather rows via tok2pix + LN;  1 = plain rows;  2 = plain rows + LN
// ADT:   0 = A f32, 1 = A bf16
// EPI:   0 = +bias, split q|k|v bf16 [which][pair][49][32] (LDS-transposed stores)
//        1 = +bias + x residual (f32), scatter f32 via tok2pix
//        2 = +bias, exact GELU, bf16 h [row][1024]       (LDS-transposed stores)
//        3 = +bias + resid (f32), f32 out [row][256]
template<int AMODE, int ADT, int EPI>
__global__ void gemm_kernel(
    const void* __restrict__ Av, const u16* __restrict__ Bt,
    const float* __restrict__ stats, const float* __restrict__ biasf,
    const float* __restrict__ resid, void* __restrict__ outv, int K, int NT)
{
  constexpr int BM=128, BN=128, BKt=64;
  __shared__ u16 smem[BM*BKt + BN*BKt];   // As | Bs ; reused as Cs (128x128 bf16)
  u16* As = smem;
  u16* Bs = smem + BM*BKt;
  int bid = blockIdx.x;
  int mt = bid / NT, nt = bid - mt*NT;
  int m0 = mt*BM, n0 = nt*BN;
  int tid  = threadIdx.x;
  int lane = tid & 63, wave = tid >> 6;
  int wr = wave >> 1, wc = wave & 1;

  f32x4 acc[4][4];
  #pragma unroll
  for (int i=0;i<4;i++)
    #pragma unroll
    for (int j=0;j<4;j++){ acc[i][j][0]=0.f; acc[i][j][1]=0.f; acc[i][j][2]=0.f; acc[i][j][3]=0.f; }

  for (int kt=0; kt<K; kt+=BKt){
    #pragma unroll
    for (int i=0;i<4;i++){                       // stage A (optional LN), to bf16
      int c = tid + i*256;
      int row = c >> 3, k8 = (c & 7)*8;
      int grow = (AMODE==0) ? tok2pix(m0+row) : (m0+row);
      float fv[8];
      if (ADT == 0){
        const float* ap = (const float*)Av + (size_t)grow*K + kt + k8;
        f4 a0 = *(const f4*)ap, a1 = *(const f4*)(ap+4);
        #pragma unroll
        for (int e=0;e<4;e++){ fv[e]=a0[e]; fv[4+e]=a1[e]; }
      } else {
        us8 v = *(const us8*)((const u16*)Av + (size_t)grow*K + kt + k8);
        #pragma unroll
        for (int e=0;e<8;e++) fv[e] = bf2f(v[e]);
      }
      if (AMODE != 1){
        float mean = stats[2*grow], rstd = stats[2*grow+1];
        #pragma unroll
        for (int e=0;e<8;e++) fv[e] = (fv[e]-mean)*rstd;
      }
      us8 o;
      #pragma unroll
      for (int e=0;e<8;e++) o[e] = f2bf(fv[e]);
      *(us8*)(As + row*BKt + k8) = o;
    }
    #pragma unroll
    for (int i=0;i<4;i++){                       // stage B (prepped bf16)
      int c = tid + i*256;
      int row = c >> 3, k8 = (c & 7)*8;
      *(us8*)(Bs + row*BKt + k8) = *(const us8*)(Bt + (size_t)(n0+row)*K + kt + k8);
    }
    __syncthreads();
    #pragma unroll
    for (int kk=0; kk<2; kk++){
      bf16x8 af[4], bfr[4];
      #pragma unroll
      for (int mi=0;mi<4;mi++){
        int r = wr*64 + mi*16 + (lane & 15);
        af[mi] = *(const bf16x8*)(As + r*BKt + kk*32 + (lane>>4)*8);
      }
      #pragma unroll
      for (int ni=0;ni<4;ni++){
        int r = wc*64 + ni*16 + (lane & 15);
        bfr[ni] = *(const bf16x8*)(Bs + r*BKt + kk*32 + (lane>>4)*8);
      }
      #pragma unroll
      for (int mi=0;mi<4;mi++)
        #pragma unroll
        for (int ni=0;ni<4;ni++)
          acc[mi][ni] = __builtin_amdgcn_mfma_f32_16x16x32_bf16(af[mi], bfr[ni], acc[mi][ni], 0, 0, 0);
    }
    __syncthreads();
  }

  int lr = lane >> 4, lc = lane & 15;
  if (EPI==0 || EPI==2){
    // transpose C through LDS (swizzled), then full-line us8 global stores
    u16* Cs = smem;                               // 128x128 bf16 = 32 KB
    #pragma unroll
    for (int mi=0;mi<4;mi++){
      #pragma unroll
      for (int ni=0;ni<4;ni++){
        int cl = wc*64 + ni*16 + lc;
        float bv = biasf[n0 + cl];
        #pragma unroll
        for (int j=0;j<4;j++){
          int rl = wr*64 + mi*16 + lr*4 + j;
          float v = acc[mi][ni][j] + bv;
          if (EPI==2) v = 0.5f*v*(1.f + erff(v*0.70710678118654752f));
          u32 byte = (u32)(rl*256 + cl*2) ^ ((u32)(rl&7)<<4);
          Cs[byte>>1] = f2bf(v);
        }
      }
    }
    __syncthreads();
    #pragma unroll
    for (int i=0;i<8;i++){
      int c = tid + i*256;                        // 0..2047 : 128 rows x 16 chunks
      int rl = c>>4, c0 = (c&15)*8;
      u32 byte = (u32)(rl*256 + c0*2) ^ ((u32)(rl&7)<<4);
      us8 v = *(const us8*)(Cs + (byte>>1));
      int row = m0 + rl, col = n0 + c0;
      if (EPI==0){
        int which = col>>8, hh = (col>>5)&7, d0 = col&31;
        int bwi = row/49, t = row - bwi*49;
        *(us8*)((u16*)outv + ((size_t)which*NPAIR + bwi*8 + hh)*(WA*32) + t*32 + d0) = v;
      } else {
        *(us8*)((u16*)outv + (size_t)row*1024 + col) = v;
      }
    }
  } else {
    #pragma unroll
    for (int mi=0;mi<4;mi++){
      #pragma unroll
      for (int ni=0;ni<4;ni++){
        int col = n0 + wc*64 + ni*16 + lc;
        #pragma unroll
        for (int j=0;j<4;j++){
          int row = m0 + wr*64 + mi*16 + lr*4 + j;
          float v = acc[mi][ni][j] + biasf[col];
          if (EPI==1){
            int pix = tok2pix(row);
            v += resid[(size_t)pix*256 + col];
            ((float*)outv)[(size_t)pix*256 + col] = v;
          } else {
            v += resid[(size_t)row*256 + col];
            ((float*)outv)[(size_t)row*256 + col] = v;
          }
        }
      }
    }
  }
}

// ---------------- MFMA windowed attention: one wave per (window, head) ----------------
__global__ void attn_mfma_kernel(
    const u16* __restrict__ qkv,    // [3][NPAIR][49][32] bf16
    const float* __restrict__ rpb,  // [169][8]
    const int* __restrict__ rel,    // [49][49]
    const float* __restrict__ mask, // [64][49][49]
    u16* __restrict__ outb)         // [NTOK][256] bf16 (window-token order)
{
  __shared__ u16 Kls[4][64*32];   // K rows (pad 64), 64B stride: frag reads at bank floor
  __shared__ u16 Vt [4][32*64];   // V^T [d][k], 128B stride, swizzle ^((d&7)<<4)
  __shared__ u16 Pls[4][64*64];   // P  [i][j], 128B stride, swizzle ^((i&7)<<4)
  int wave = threadIdx.x>>6, lane = threadIdx.x&63;
  int pair = blockIdx.x*4 + wave;
  int bw = pair>>3, h = pair&7, w = bw&63;
  int lc = lane&15, g = lane>>4;
  const u16* qg = qkv + (size_t)pair*(WA*32);
  const u16* kg = qg + (size_t)NPAIR*(WA*32);
  const u16* vg = qg + (size_t)2*NPAIR*(WA*32);
  u16* Kp = &Kls[wave][0];
  u16* Vp = &Vt[wave][0];
  u16* Pp = &Pls[wave][0];

  // ---- stage K (zero-padded to 64 rows) and V^T (zero-padded to 64 k) ----
  #pragma unroll
  for (int i=0;i<4;i++){
    int idx = i*64 + lane;
    int r = idx>>2, seg = idx&3;
    us8 kv, vv;
    if (r < WA){
      kv = *(const us8*)(kg + r*32 + seg*8);
      vv = *(const us8*)(vg + r*32 + seg*8);
    } else {
      #pragma unroll
      for (int e=0;e<8;e++){ kv[e]=0; vv[e]=0; }
    }
    *(us8*)(Kp + r*32 + seg*8) = kv;
    #pragma unroll
    for (int e=0;e<8;e++){
      int d = seg*8 + e;
      u32 byte = ((u32)(d*128 + r*2)) ^ ((u32)(d&7)<<4);
      Vp[byte>>1] = vv[e];
    }
  }

  // ---- Q fragments (direct from global, zero pad rows >= 49) ----
  bf16x8 qa[4];
  #pragma unroll
  for (int mi=0;mi<4;mi++){
    int r = mi*16 + lc;
    if (r < WA) qa[mi] = *(const bf16x8*)(qg + r*32 + g*8);
    else { bf16x8 z; 
           #pragma unroll
           for (int e=0;e<8;e++) z[e]=0; qa[mi]=z; }
  }

  // ---- S = Q K^T : 16 MFMAs ----
  f32x4 acc[4][4];
  #pragma unroll
  for (int i=0;i<4;i++)
    #pragma unroll
    for (int j=0;j<4;j++){ acc[i][j][0]=0.f; acc[i][j][1]=0.f; acc[i][j][2]=0.f; acc[i][j][3]=0.f; }
  #pragma unroll
  for (int ni=0;ni<4;ni++){
    bf16x8 kb = *(const bf16x8*)(Kp + (ni*16+lc)*32 + g*8);
    #pragma unroll
    for (int mi=0;mi<4;mi++)
      acc[mi][ni] = __builtin_amdgcn_mfma_f32_16x16x32_bf16(qa[mi], kb, acc[mi][ni], 0, 0, 0);
  }

  // ---- scale + rel-pos bias + shift mask + softmax (16-lane group reduce) ----
  const float scale = 0.17677669529663689f;   // 1/sqrt(32)
  float rinv[4][4];
  #pragma unroll
  for (int mi=0;mi<4;mi++){
    #pragma unroll
    for (int jr=0;jr<4;jr++){
      int i = mi*16 + g*4 + jr;
      float sv[4];
      #pragma unroll
      for (int ni=0;ni<4;ni++){
        int j = ni*16 + lc;
        float s;
        if (i < WA && j < WA){
          s = acc[mi][ni][jr]*scale + rpb[rel[i*WA+j]*8 + h] + mask[((size_t)w*WA + i)*WA + j];
        } else s = -1e9f;
        sv[ni] = s;
      }
      float mx = fmaxf(fmaxf(sv[0],sv[1]), fmaxf(sv[2],sv[3]));
      #pragma unroll
      for (int off=1; off<16; off<<=1) mx = fmaxf(mx, __shfl_xor(mx, off, 64));
      float sum = 0.f;
      #pragma unroll
      for (int ni=0;ni<4;ni++){ sv[ni] = __expf(sv[ni]-mx); sum += sv[ni]; }
      #pragma unroll
      for (int off=1; off<16; off<<=1) sum += __shfl_xor(sum, off, 64);
      rinv[mi][jr] = 1.f/sum;
      #pragma unroll
      for (int ni=0;ni<4;ni++){
        int j = ni*16 + lc;
        u32 byte = ((u32)(i*128 + j*2)) ^ ((u32)(i&7)<<4);
        Pp[byte>>1] = f2bf(sv[ni]);
      }
    }
  }

  // ---- O = P V : 16 MFMAs (K=64 over j) ----
  bf16x8 vb[2][2];
  #pragma unroll
  for (int kk=0;kk<2;kk++)
    #pragma unroll
    for (int ni=0;ni<2;ni++){
      int d = ni*16 + lc;
      u32 byte = ((u32)(d*128 + kk*64 + g*16)) ^ ((u32)(d&7)<<4);
      vb[kk][ni] = *(const bf16x8*)(Vp + (byte>>1));
    }
  f32x4 aco[4][2];
  #pragma unroll
  for (int i=0;i<4;i++)
    #pragma unroll
    for (int j=0;j<2;j++){ aco[i][j][0]=0.f; aco[i][j][1]=0.f; aco[i][j][2]=0.f; aco[i][j][3]=0.f; }
  #pragma unroll
  for (int mi=0;mi<4;mi++){
    int r = mi*16 + lc;
    #pragma unroll
    for (int kk=0;kk<2;kk++){
      u32 byte = ((u32)(r*128 + kk*64 + g*16)) ^ ((u32)(r&7)<<4);
      bf16x8 pa = *(const bf16x8*)(Pp + (byte>>1));
      #pragma unroll
      for (int ni=0;ni<2;ni++)
        aco[mi][ni] = __builtin_amdgcn_mfma_f32_16x16x32_bf16(pa, vb[kk][ni], aco[mi][ni], 0, 0, 0);
    }
  }

  // ---- normalize, stage O in LDS (reuse Kls), coalesced global store ----
  u16* Op = Kp;
  #pragma unroll
  for (int mi=0;mi<4;mi++){
    #pragma unroll
    for (int jr=0;jr<4;jr++){
      int i = mi*16 + g*4 + jr;
      if (i < WA){
        float rv = rinv[mi][jr];
        #pragma unroll
        for (int ni=0;ni<2;ni++)
          Op[i*32 + ni*16 + lc] = f2bf(aco[mi][ni][jr]*rv);
      }
    }
  }
  size_t obase = (size_t)(bw*WA)*256 + h*32;
  #pragma unroll
  for (int i=0;i<4;i++){
    int c = i*64 + lane;
    if (c < WA*4){
      int t = c>>2, seg = c&3;
      *(us8*)(outb + obase + (size_t)t*256 + seg*8) = *(const us8*)(Op + t*32 + seg*8);
    }
  }
}

extern "C" void kernel_launch(void* const* d_in, const int* in_sizes, int n_in,
                              void* d_out, int out_size, void* d_ws, size_t ws_size,
                              hipStream_t stream) {
  const float* x      = (const float*)d_in[0];
  const float* ln1w   = (const float*)d_in[1];
  const float* ln1b   = (const float*)d_in[2];
  const float* qkv_w  = (const float*)d_in[3];
  const float* qkv_b  = (const float*)d_in[4];
  const float* rpb    = (const float*)d_in[5];
  const float* proj_w = (const float*)d_in[6];
  const float* proj_b = (const float*)d_in[7];
  const float* ln2w   = (const float*)d_in[8];
  const float* ln2b   = (const float*)d_in[9];
  const float* fc1_w  = (const float*)d_in[10];
  const float* fc1_b  = (const float*)d_in[11];
  const float* ln3w   = (const float*)d_in[12];
  const float* ln3b   = (const float*)d_in[13];
  const float* fc2_w  = (const float*)d_in[14];
  const float* fc2_b  = (const float*)d_in[15];
  const float* amask  = (const float*)d_in[16];
  const int*   rel    = (const int*)d_in[17];
  float* out = (float*)d_out;

  char* ws = (char*)d_ws;
  float* statsA = (float*)(ws);                        // 100352*2*4 = 802816
  float* statsB = (float*)(ws +  802816);
  float* statsC = (float*)(ws + 1605632);
  float* bq     = (float*)(ws + 2408448);
  float* b1     = (float*)(ws + 2411520);
  float* b2     = (float*)(ws + 2415616);
  float* bp     = (float*)(ws + 2416640);
  u16*   wq     = (u16*)  (ws + 2417664);              // 768*256*2
  u16*   w1     = (u16*)  (ws + 2810880);              // 1024*256*2
  u16*   w2     = (u16*)  (ws + 3335168);              // 256*1024*2
  u16*   wp     = (u16*)  (ws + 3859456);              // 256*256*2
  u16*   qkvbuf = (u16*)  (ws + 3990528);              // 3*NPAIR*49*32*2 = 154140672
  u16*   attno  = (u16*)  (ws + 3990528 + 154140672);  // NTOK*256*2
  u16*   hbuf   = (u16*)  (ws + 3990528);              // NTOK*1024*2 (aliases qkvbuf+attno)

  prep_weights<<<576,256,0,stream>>>(qkv_w,qkv_b,ln1w,ln1b, fc1_w,fc1_b,ln2w,ln2b,
                                     fc2_w,fc2_b,ln3w,ln3b, proj_w,proj_b,
                                     wq,bq, w1,b1, w2,b2, wp,bp);
  ln_stats_kernel<256,0><<<NTOK/4,256,0,stream>>>(x, statsA);
  gemm_kernel<0,0,0><<<784*6,256,0,stream>>>(x, wq, statsA, bq, nullptr, qkvbuf, 256, 6);
  attn_mfma_kernel<<<NPAIR/4,256,0,stream>>>(qkvbuf, rpb, rel, amask, attno);
  gemm_kernel<1,1,1><<<784*2,256,0,stream>>>(attno, wp, nullptr, bp, x, out, 256, 2);
  ln_stats_kernel<256,0><<<NTOK/4,256,0,stream>>>(out, statsB);
  gemm_kernel<2,0,2><<<784*8,256,0,stream>>>(out, w1, statsB, b1, nullptr, hbuf, 256, 8);
  ln_stats_kernel<1024,1><<<NTOK/4,256,0,stream>>>(hbuf, statsC);
  gemm_kernel<2,1,3><<<784*2,256,0,stream>>>(hbuf, w2, statsC, b2, out, out, 1024, 2);
}

// Round 4
// 688.070 us; speedup vs baseline: 2.2265x; 1.2877x over previous
//
#include <hip/hip_runtime.h>
#include <hip/hip_bf16.h>
#include <math.h>

typedef __attribute__((ext_vector_type(8))) short bf16x8;
typedef __attribute__((ext_vector_type(4))) float f32x4;
typedef __attribute__((ext_vector_type(4))) float f4;
typedef __attribute__((ext_vector_type(8))) unsigned short us8;
typedef __attribute__((ext_vector_type(4))) unsigned short us4;
typedef unsigned short u16;
typedef unsigned int u32;

#define HEADS 8
#define SHIFT_ 3
#define HIMG 56
#define WIMG 56
#define WA 49
#define NTOK 100352   // 32*56*56
#define NPAIR 16384   // 2048 windows * 8 heads

static __device__ __forceinline__ float bf2f(u16 v){ return __uint_as_float(((u32)v)<<16); }
static __device__ __forceinline__ u16 f2bf(float f){
  u32 u = __float_as_uint(f);
  return (u16)((u + 0x7fffu + ((u>>16)&1u)) >> 16);
}
static __device__ __forceinline__ float wsum(float v){
  #pragma unroll
  for (int off=32; off>0; off>>=1) v += __shfl_xor(v, off, 64);
  return v;
}
// async global->LDS, 16 bytes per lane; LDS dest = wave-uniform base + lane*16
static __device__ __forceinline__ void glds16(const u16* g, u16* l){
  __builtin_amdgcn_global_load_lds(
      (const __attribute__((address_space(1))) unsigned int*)g,
      (__attribute__((address_space(3))) unsigned int*)l, 16, 0, 0);
}
// token index (window order, shifted) -> pixel index (raster order).
static __device__ __forceinline__ int tok2pix(int row){
  int bw = row / 49, t = row - bw*49;
  int b  = bw >> 6,  w = bw & 63;
  int wh = w >> 3,   ww = w & 7;
  int th = t / 7,    tw = t - th*7;
  int r = wh*7 + th + SHIFT_; if (r >= HIMG) r -= HIMG;
  int c = ww*7 + tw + SHIFT_; if (c >= WIMG) c -= WIMG;
  return (b*HIMG + r)*WIMG + c;
}

// ---------------- LN stats (for fc2's reg-staged path) ----------------
template<int C, int ISBF>
__global__ void ln_stats_kernel(const void* __restrict__ srcv, float* __restrict__ stats){
  int wave = threadIdx.x >> 6, lane = threadIdx.x & 63;
  int tok = blockIdx.x*4 + wave;
  float s=0.f, s2=0.f;
  if (ISBF == 0){
    const float* p = (const float*)srcv + (size_t)tok*C;
    #pragma unroll
    for (int i=0;i<C/256;i++){
      f4 v = *(const f4*)(p + lane*4*(C/256) + i*4);
      #pragma unroll
      for (int e=0;e<4;e++){ float f=v[e]; s+=f; s2+=f*f; }
    }
  } else {
    const u16* p = (const u16*)srcv + (size_t)tok*C;
    #pragma unroll
    for (int i=0;i<C/512;i++){
      us8 v = *(const us8*)(p + lane*8*(C/512) + i*8);
      #pragma unroll
      for (int e=0;e<8;e++){ float f=bf2f(v[e]); s+=f; s2+=f*f; }
    }
  }
  s = wsum(s); s2 = wsum(s2);
  if (lane==0){
    float mean = s/(float)C;
    float var  = s2/(float)C - mean*mean;
    stats[2*tok]   = mean;
    stats[2*tok+1] = rsqrtf(var + 1e-5f);
  }
}

// ---------------- fused LN stats+apply: f32 [tok][256] -> bf16 normalized ----------------
__global__ void ln_apply_kernel(const float* __restrict__ src, u16* __restrict__ dst){
  int wave = threadIdx.x >> 6, lane = threadIdx.x & 63;
  int tok = blockIdx.x*4 + wave;
  const float* p = src + (size_t)tok*256;
  f4 a = *(const f4*)(p + lane*4);
  float s = a[0]+a[1]+a[2]+a[3];
  float s2 = a[0]*a[0]+a[1]*a[1]+a[2]*a[2]+a[3]*a[3];
  s = wsum(s); s2 = wsum(s2);
  float mean = s*(1.f/256.f);
  float var  = s2*(1.f/256.f) - mean*mean;
  float rstd = rsqrtf(var + 1e-5f);
  us4 o;
  #pragma unroll
  for (int e=0;e<4;e++) o[e] = f2bf((a[e]-mean)*rstd);
  *(us4*)(dst + (size_t)tok*256 + lane*4) = o;
}

// ------------- fold LN affine into weights -------------
__global__ void prep_weights(
    const float* __restrict__ qkv_w, const float* __restrict__ qkv_b,
    const float* __restrict__ ln1w,  const float* __restrict__ ln1b,
    const float* __restrict__ fc1_w, const float* __restrict__ fc1_b,
    const float* __restrict__ ln2w,  const float* __restrict__ ln2b,
    const float* __restrict__ fc2_w, const float* __restrict__ fc2_b,
    const float* __restrict__ ln3w,  const float* __restrict__ ln3b,
    const float* __restrict__ proj_w, const float* __restrict__ proj_b,
    u16* __restrict__ wq, float* __restrict__ bq,
    u16* __restrict__ w1, float* __restrict__ b1,
    u16* __restrict__ w2, float* __restrict__ b2,
    u16* __restrict__ wp, float* __restrict__ bp)
{
  int wave = threadIdx.x>>6, lane = threadIdx.x&63;
  int n = blockIdx.x*4 + wave;            // 0..2303
  const float *W,*lw,*lb,*bs; u16* WO; float* BO; int K, row, noln;
  if (n < 768)      { W=qkv_w; lw=ln1w; lb=ln1b; bs=qkv_b; WO=wq; BO=bq; K=256;  row=n;      noln=0; }
  else if (n < 1792){ W=fc1_w; lw=ln2w; lb=ln2b; bs=fc1_b; WO=w1; BO=b1; K=256;  row=n-768;  noln=0; }
  else if (n < 2048){ W=fc2_w; lw=ln3w; lb=ln3b; bs=fc2_b; WO=w2; BO=b2; K=1024; row=n-1792; noln=0; }
  else              { W=proj_w; lw=nullptr; lb=nullptr; bs=proj_b; WO=wp; BO=bp; K=256; row=n-2048; noln=1; }
  float dot = 0.f;
  for (int k=lane; k<K; k+=64){
    float wv = W[(size_t)row*K + k];
    if (noln){
      WO[(size_t)row*K + k] = f2bf(wv);
    } else {
      dot += wv * lb[k];
      WO[(size_t)row*K + k] = f2bf(wv * lw[k]);
    }
  }
  dot = wsum(dot);
  if (lane==0) BO[row] = bs[row] + dot;
}

// ---------------- GEMM v3: C = A @ Bt^T (+bias, +epilogue) ----------------
// SMODE: 0 = glds A, gathered rows (tok2pix), bf16 src
//        1 = glds A, linear rows, bf16 src
//        2 = reg-staged A + LN, bf16 src (fc2)
//        3 = reg-staged A + LN, f32 src (fc1 fallback)
// EPI:   0 = +bias, split q|k|v bf16 [which][pair][49][32] (LDS-transposed stores)
//        1 = +bias + x residual (f32), scatter f32 via tok2pix
//        2 = +bias, exact GELU, bf16 h [row][1024]         (LDS-transposed stores)
//        3 = +bias + resid (f32), f32 out [row][256]
template<int SMODE, int EPI>
__global__ void gemm3(
    const void* __restrict__ Av, const u16* __restrict__ Bt,
    const float* __restrict__ stats, const float* __restrict__ biasf,
    const float* __restrict__ resid, void* __restrict__ outv,
    int K, int NT, int CHUNK)
{
  constexpr int BM=128, BN=128, BK=64;
  __shared__ u16 smem[BM*BK + BN*BK];   // As | Bs ; reused as Cs (128x128 bf16)
  u16* As = smem;
  u16* Bs = smem + BM*BK;
  // XCD-chunked mapping: all NT column tiles of an M-tile run consecutively on one XCD
  int b = blockIdx.x;
  int linear = (b & 7)*CHUNK + (b >> 3);
  int mt = linear / NT, nt = linear - mt*NT;
  int m0 = mt*BM, n0 = nt*BN;
  int tid  = threadIdx.x;
  int lane = tid & 63, wave = tid >> 6;
  int wr = wave >> 1, wc = wave & 1;

  // precomputed per-lane staging sources (chunk c = tid + i*256 -> 16B at LDS byte c*16)
  const u16* asrc[4];
  const u16* bsrc[4];
  #pragma unroll
  for (int i=0;i<4;i++){
    int c = tid + i*256;
    int row = c >> 3, ch = c & 7;
    if (SMODE <= 1){
      int grow = (SMODE==0) ? tok2pix(m0+row) : (m0+row);
      asrc[i] = (const u16*)Av + (size_t)grow*K + ch*8;
    }
    bsrc[i] = Bt + (size_t)(n0+row)*K + ch*8;
  }

  f32x4 acc[4][4];
  #pragma unroll
  for (int i=0;i<4;i++)
    #pragma unroll
    for (int j=0;j<4;j++){ acc[i][j][0]=0.f; acc[i][j][1]=0.f; acc[i][j][2]=0.f; acc[i][j][3]=0.f; }

  for (int kt=0; kt<K; kt+=BK){
    if (SMODE <= 1){
      #pragma unroll
      for (int i=0;i<4;i++) glds16(asrc[i]+kt, As + i*2048 + wave*512);
    } else {
      #pragma unroll
      for (int i=0;i<4;i++){
        int c = tid + i*256;
        int row = c >> 3, k8 = (c & 7)*8;
        int grow = m0 + row;
        float fv[8];
        if (SMODE == 3){
          const float* ap = (const float*)Av + (size_t)grow*K + kt + k8;
          f4 a0 = *(const f4*)ap, a1 = *(const f4*)(ap+4);
          #pragma unroll
          for (int e=0;e<4;e++){ fv[e]=a0[e]; fv[4+e]=a1[e]; }
        } else {
          us8 v = *(const us8*)((const u16*)Av + (size_t)grow*K + kt + k8);
          #pragma unroll
          for (int e=0;e<8;e++) fv[e] = bf2f(v[e]);
        }
        float mean = stats[2*grow], rstd = stats[2*grow+1];
        us8 o;
        #pragma unroll
        for (int e=0;e<8;e++) o[e] = f2bf((fv[e]-mean)*rstd);
        *(us8*)(As + row*BK + k8) = o;
      }
    }
    #pragma unroll
    for (int i=0;i<4;i++) glds16(bsrc[i]+kt, Bs + i*2048 + wave*512);
    __syncthreads();
    #pragma unroll
    for (int kk=0; kk<2; kk++){
      bf16x8 af[4], bfr[4];
      #pragma unroll
      for (int mi=0;mi<4;mi++){
        int r = wr*64 + mi*16 + (lane & 15);
        af[mi] = *(const bf16x8*)(As + r*BK + kk*32 + (lane>>4)*8);
      }
      #pragma unroll
      for (int ni=0;ni<4;ni++){
        int r = wc*64 + ni*16 + (lane & 15);
        bfr[ni] = *(const bf16x8*)(Bs + r*BK + kk*32 + (lane>>4)*8);
      }
      #pragma unroll
      for (int mi=0;mi<4;mi++)
        #pragma unroll
        for (int ni=0;ni<4;ni++)
          acc[mi][ni] = __builtin_amdgcn_mfma_f32_16x16x32_bf16(af[mi], bfr[ni], acc[mi][ni], 0, 0, 0);
    }
    __syncthreads();
  }

  int lr = lane >> 4, lc = lane & 15;
  if (EPI==0 || EPI==2){
    u16* Cs = smem;                               // 128x128 bf16 = 32 KB
    #pragma unroll
    for (int mi=0;mi<4;mi++){
      #pragma unroll
      for (int ni=0;ni<4;ni++){
        int cl = wc*64 + ni*16 + lc;
        float bv = biasf[n0 + cl];
        #pragma unroll
        for (int j=0;j<4;j++){
          int rl = wr*64 + mi*16 + lr*4 + j;
          float v = acc[mi][ni][j] + bv;
          if (EPI==2) v = 0.5f*v*(1.f + erff(v*0.70710678118654752f));
          u32 byte = (u32)(rl*256 + cl*2) ^ ((u32)(rl&7)<<4);
          Cs[byte>>1] = f2bf(v);
        }
      }
    }
    __syncthreads();
    #pragma unroll
    for (int i=0;i<8;i++){
      int c = tid + i*256;                        // 128 rows x 16 chunks
      int rl = c>>4, c0 = (c&15)*8;
      u32 byte = (u32)(rl*256 + c0*2) ^ ((u32)(rl&7)<<4);
      us8 v = *(const us8*)(Cs + (byte>>1));
      int row = m0 + rl, col = n0 + c0;
      if (EPI==0){
        int which = col>>8, hh = (col>>5)&7, d0 = col&31;
        int bwi = row/49, t = row - bwi*49;
        *(us8*)((u16*)outv + ((size_t)which*NPAIR + bwi*8 + hh)*(WA*32) + t*32 + d0) = v;
      } else {
        *(us8*)((u16*)outv + (size_t)row*1024 + col) = v;
      }
    }
  } else {
    #pragma unroll
    for (int mi=0;mi<4;mi++){
      #pragma unroll
      for (int ni=0;ni<4;ni++){
        int col = n0 + wc*64 + ni*16 + lc;
        #pragma unroll
        for (int j=0;j<4;j++){
          int row = m0 + wr*64 + mi*16 + lr*4 + j;
          float v = acc[mi][ni][j] + biasf[col];
          if (EPI==1){
            int pix = tok2pix(row);
            v += resid[(size_t)pix*256 + col];
            ((float*)outv)[(size_t)pix*256 + col] = v;
          } else {
            v += resid[(size_t)row*256 + col];
            ((float*)outv)[(size_t)row*256 + col] = v;
          }
        }
      }
    }
  }
}

// ---------------- MFMA windowed attention: one wave per (window, head) ----------------
__global__ void attn_mfma_kernel(
    const u16* __restrict__ qkv,    // [3][NPAIR][49][32] bf16
    const float* __restrict__ rpb,  // [169][8]
    const int* __restrict__ rel,    // [49][49]
    const float* __restrict__ mask, // [64][49][49]
    u16* __restrict__ outb)         // [NTOK][256] bf16 (window-token order)
{
  __shared__ u16 Kls[4][64*32];
  __shared__ u16 Vt [4][32*64];
  __shared__ u16 Pls[4][64*64];
  int wave = threadIdx.x>>6, lane = threadIdx.x&63;
  int pair = blockIdx.x*4 + wave;
  int bw = pair>>3, h = pair&7, w = bw&63;
  int lc = lane&15, g = lane>>4;
  const u16* qg = qkv + (size_t)pair*(WA*32);
  const u16* kg = qg + (size_t)NPAIR*(WA*32);
  const u16* vg = qg + (size_t)2*NPAIR*(WA*32);
  u16* Kp = &Kls[wave][0];
  u16* Vp = &Vt[wave][0];
  u16* Pp = &Pls[wave][0];

  #pragma unroll
  for (int i=0;i<4;i++){
    int idx = i*64 + lane;
    int r = idx>>2, seg = idx&3;
    us8 kv, vv;
    if (r < WA){
      kv = *(const us8*)(kg + r*32 + seg*8);
      vv = *(const us8*)(vg + r*32 + seg*8);
    } else {
      #pragma unroll
      for (int e=0;e<8;e++){ kv[e]=0; vv[e]=0; }
    }
    *(us8*)(Kp + r*32 + seg*8) = kv;
    #pragma unroll
    for (int e=0;e<8;e++){
      int d = seg*8 + e;
      u32 byte = ((u32)(d*128 + r*2)) ^ ((u32)(d&7)<<4);
      Vp[byte>>1] = vv[e];
    }
  }

  bf16x8 qa[4];
  #pragma unroll
  for (int mi=0;mi<4;mi++){
    int r = mi*16 + lc;
    if (r < WA) qa[mi] = *(const bf16x8*)(qg + r*32 + g*8);
    else { bf16x8 z;
           #pragma unroll
           for (int e=0;e<8;e++) z[e]=0; qa[mi]=z; }
  }

  f32x4 acc[4][4];
  #pragma unroll
  for (int i=0;i<4;i++)
    #pragma unroll
    for (int j=0;j<4;j++){ acc[i][j][0]=0.f; acc[i][j][1]=0.f; acc[i][j][2]=0.f; acc[i][j][3]=0.f; }
  __syncthreads();
  #pragma unroll
  for (int ni=0;ni<4;ni++){
    bf16x8 kb = *(const bf16x8*)(Kp + (ni*16+lc)*32 + g*8);
    #pragma unroll
    for (int mi=0;mi<4;mi++)
      acc[mi][ni] = __builtin_amdgcn_mfma_f32_16x16x32_bf16(qa[mi], kb, acc[mi][ni], 0, 0, 0);
  }

  const float scale = 0.17677669529663689f;   // 1/sqrt(32)
  float rinv[4][4];
  #pragma unroll
  for (int mi=0;mi<4;mi++){
    #pragma unroll
    for (int jr=0;jr<4;jr++){
      int i = mi*16 + g*4 + jr;
      float sv[4];
      #pragma unroll
      for (int ni=0;ni<4;ni++){
        int j = ni*16 + lc;
        float s;
        if (i < WA && j < WA){
          s = acc[mi][ni][jr]*scale + rpb[rel[i*WA+j]*8 + h] + mask[((size_t)w*WA + i)*WA + j];
        } else s = -1e9f;
        sv[ni] = s;
      }
      float mx = fmaxf(fmaxf(sv[0],sv[1]), fmaxf(sv[2],sv[3]));
      #pragma unroll
      for (int off=1; off<16; off<<=1) mx = fmaxf(mx, __shfl_xor(mx, off, 64));
      float sum = 0.f;
      #pragma unroll
      for (int ni=0;ni<4;ni++){ sv[ni] = __expf(sv[ni]-mx); sum += sv[ni]; }
      #pragma unroll
      for (int off=1; off<16; off<<=1) sum += __shfl_xor(sum, off, 64);
      rinv[mi][jr] = 1.f/sum;
      #pragma unroll
      for (int ni=0;ni<4;ni++){
        int j = ni*16 + lc;
        u32 byte = ((u32)(i*128 + j*2)) ^ ((u32)(i&7)<<4);
        Pp[byte>>1] = f2bf(sv[ni]);
      }
    }
  }

  bf16x8 vb[2][2];
  #pragma unroll
  for (int kk=0;kk<2;kk++)
    #pragma unroll
    for (int ni=0;ni<2;ni++){
      int d = ni*16 + lc;
      u32 byte = ((u32)(d*128 + kk*64 + g*16)) ^ ((u32)(d&7)<<4);
      vb[kk][ni] = *(const bf16x8*)(Vp + (byte>>1));
    }
  f32x4 aco[4][2];
  #pragma unroll
  for (int i=0;i<4;i++)
    #pragma unroll
    for (int j=0;j<2;j++){ aco[i][j][0]=0.f; aco[i][j][1]=0.f; aco[i][j][2]=0.f; aco[i][j][3]=0.f; }
  #pragma unroll
  for (int mi=0;mi<4;mi++){
    int r = mi*16 + lc;
    #pragma unroll
    for (int kk=0;kk<2;kk++){
      u32 byte = ((u32)(r*128 + kk*64 + g*16)) ^ ((u32)(r&7)<<4);
      bf16x8 pa = *(const bf16x8*)(Pp + (byte>>1));
      #pragma unroll
      for (int ni=0;ni<2;ni++)
        aco[mi][ni] = __builtin_amdgcn_mfma_f32_16x16x32_bf16(pa, vb[kk][ni], aco[mi][ni], 0, 0, 0);
    }
  }

  u16* Op = Kp;
  #pragma unroll
  for (int mi=0;mi<4;mi++){
    #pragma unroll
    for (int jr=0;jr<4;jr++){
      int i = mi*16 + g*4 + jr;
      if (i < WA){
        float rv = rinv[mi][jr];
        #pragma unroll
        for (int ni=0;ni<2;ni++)
          Op[i*32 + ni*16 + lc] = f2bf(aco[mi][ni][jr]*rv);
      }
    }
  }
  __syncthreads();
  size_t obase = (size_t)(bw*WA)*256 + h*32;
  #pragma unroll
  for (int i=0;i<4;i++){
    int c = i*64 + lane;
    if (c < WA*4){
      int t = c>>2, seg = c&3;
      *(us8*)(outb + obase + (size_t)t*256 + seg*8) = *(const us8*)(Op + t*32 + seg*8);
    }
  }
}

extern "C" void kernel_launch(void* const* d_in, const int* in_sizes, int n_in,
                              void* d_out, int out_size, void* d_ws, size_t ws_size,
                              hipStream_t stream) {
  const float* x      = (const float*)d_in[0];
  const float* ln1w   = (const float*)d_in[1];
  const float* ln1b   = (const float*)d_in[2];
  const float* qkv_w  = (const float*)d_in[3];
  const float* qkv_b  = (const float*)d_in[4];
  const float* rpb    = (const float*)d_in[5];
  const float* proj_w = (const float*)d_in[6];
  const float* proj_b = (const float*)d_in[7];
  const float* ln2w   = (const float*)d_in[8];
  const float* ln2b   = (const float*)d_in[9];
  const float* fc1_w  = (const float*)d_in[10];
  const float* fc1_b  = (const float*)d_in[11];
  const float* ln3w   = (const float*)d_in[12];
  const float* ln3b   = (const float*)d_in[13];
  const float* fc2_w  = (const float*)d_in[14];
  const float* fc2_b  = (const float*)d_in[15];
  const float* amask  = (const float*)d_in[16];
  const int*   rel    = (const int*)d_in[17];
  float* out = (float*)d_out;

  char* ws = (char*)d_ws;
  float* statsC = (float*)(ws);                        // 802816
  float* statsB = (float*)(ws +  802816);              // 802816
  float* bq     = (float*)(ws + 1605632);              // 3072
  float* b1     = (float*)(ws + 1608704);              // 4096
  float* b2     = (float*)(ws + 1612800);              // 1024
  float* bp     = (float*)(ws + 1613824);              // 1024
  u16*   wq     = (u16*)  (ws + 1614848);              // 393216
  u16*   w1     = (u16*)  (ws + 2008064);              // 524288
  u16*   w2     = (u16*)  (ws + 2532352);              // 524288
  u16*   wp     = (u16*)  (ws + 3056640);              // 131072
  const size_t P0 = 3187712;
  u16*   qkvbuf = (u16*)(ws + P0);                     // 154140672 (live: qkv->attn)
  u16*   attno  = (u16*)(ws + P0 + 154140672);         // 51380224  (live: attn->proj)
  u16*   xb     = (u16*)(ws + P0 + 154140672);         // aliases attno slot (live: ln1->qkv)
  u16*   hbuf   = (u16*)(ws + P0);                     // 205520896 (live: fc1->fc2), aliases qkv+attno
  u16*   x1b    = (u16*)(ws + P0 + 205520896);         // 51380224  (only if ws allows)
  const int bigws = (ws_size >= (size_t)(P0 + 205520896ull + 51380224ull));

  prep_weights<<<576,256,0,stream>>>(qkv_w,qkv_b,ln1w,ln1b, fc1_w,fc1_b,ln2w,ln2b,
                                     fc2_w,fc2_b,ln3w,ln3b, proj_w,proj_b,
                                     wq,bq, w1,b1, w2,b2, wp,bp);
  // LN1 fused stats+apply -> bf16 xb (pixel order)
  ln_apply_kernel<<<NTOK/4,256,0,stream>>>(x, xb);
  // QKV: gather rows of xb via tok2pix, glds staging
  gemm3<0,0><<<784*6,256,0,stream>>>(xb, wq, nullptr, bq, nullptr, qkvbuf, 256, 6, 588);
  attn_mfma_kernel<<<NPAIR/4,256,0,stream>>>(qkvbuf, rpb, rel, amask, attno);
  // proj: attno @ wp -> scatter f32 out = x + proj
  gemm3<1,1><<<784*2,256,0,stream>>>(attno, wp, nullptr, bp, x, out, 256, 2, 196);
  if (bigws){
    // LN2 fused stats+apply -> bf16 x1b; fc1 uses glds
    ln_apply_kernel<<<NTOK/4,256,0,stream>>>(out, x1b);
    gemm3<1,2><<<784*8,256,0,stream>>>(x1b, w1, nullptr, b1, nullptr, hbuf, 256, 8, 784);
  } else {
    ln_stats_kernel<256,0><<<NTOK/4,256,0,stream>>>(out, statsB);
    gemm3<3,2><<<784*8,256,0,stream>>>(out, w1, statsB, b1, nullptr, hbuf, 256, 8, 784);
  }
  ln_stats_kernel<1024,1><<<NTOK/4,256,0,stream>>>(hbuf, statsC);
  // fc2: reg-staged LN on hbuf, +resid, f32 out
  gemm3<2,3><<<784*2,256,0,stream>>>(hbuf, w2, statsC, b2, out, out, 1024, 2, 196);
}

// Round 6
// 625.776 us; speedup vs baseline: 2.4482x; 1.0995x over previous
//
#include <hip/hip_runtime.h>
#include <hip/hip_bf16.h>
#include <math.h>

typedef __attribute__((ext_vector_type(8))) short bf16x8;
typedef __attribute__((ext_vector_type(4))) float f32x4;
typedef __attribute__((ext_vector_type(4))) float f4;
typedef __attribute__((ext_vector_type(8))) unsigned short us8;
typedef __attribute__((ext_vector_type(4))) unsigned short us4;
typedef unsigned short u16;
typedef unsigned int u32;

#define HEADS 8
#define SHIFT_ 3
#define HIMG 56
#define WIMG 56
#define WA 49
#define NTOK 100352
#define NPAIR 16384

static __device__ __forceinline__ float bf2f(u16 v){ return __uint_as_float(((u32)v)<<16); }
static __device__ __forceinline__ u16 f2bf(float f){
  u32 u = __float_as_uint(f);
  return (u16)((u + 0x7fffu + ((u>>16)&1u)) >> 16);
}
static __device__ __forceinline__ float wsum(float v){
  #pragma unroll
  for (int off=32; off>0; off>>=1) v += __shfl_xor(v, off, 64);
  return v;
}
static __device__ __forceinline__ void glds16(const u16* g, u16* l){
  __builtin_amdgcn_global_load_lds(
      (const __attribute__((address_space(1))) unsigned int*)g,
      (__attribute__((address_space(3))) unsigned int*)l, 16, 0, 0);
}
static __device__ __forceinline__ int tok2pix(int row){
  int bw = row / 49, t = row - bw*49;
  int b  = bw >> 6,  w = bw & 63;
  int wh = w >> 3,   ww = w & 7;
  int th = t / 7,    tw = t - th*7;
  int r = wh*7 + th + SHIFT_; if (r >= HIMG) r -= HIMG;
  int c = ww*7 + tw + SHIFT_; if (c >= WIMG) c -= WIMG;
  return (b*HIMG + r)*WIMG + c;
}

// ---------------- LN stats ----------------
template<int C, int ISBF>
__global__ void ln_stats_kernel(const void* __restrict__ srcv, float* __restrict__ stats){
  int wave = threadIdx.x >> 6, lane = threadIdx.x & 63;
  int tok = blockIdx.x*4 + wave;
  float s=0.f, s2=0.f;
  if (ISBF == 0){
    const float* p = (const float*)srcv + (size_t)tok*C;
    #pragma unroll
    for (int i=0;i<C/256;i++){
      f4 v = *(const f4*)(p + lane*4*(C/256) + i*4);
      #pragma unroll
      for (int e=0;e<4;e++){ float f=v[e]; s+=f; s2+=f*f; }
    }
  } else {
    const u16* p = (const u16*)srcv + (size_t)tok*C;
    #pragma unroll
    for (int i=0;i<C/512;i++){
      us8 v = *(const us8*)(p + lane*8*(C/512) + i*8);
      #pragma unroll
      for (int e=0;e<8;e++){ float f=bf2f(v[e]); s+=f; s2+=f*f; }
    }
  }
  s = wsum(s); s2 = wsum(s2);
  if (lane==0){
    float mean = s/(float)C;
    float var  = s2/(float)C - mean*mean;
    stats[2*tok]   = mean;
    stats[2*tok+1] = rsqrtf(var + 1e-5f);
  }
}

// ---------------- fused LN stats+apply: f32 [tok][256] -> bf16 normalized ----------------
__global__ void ln_apply_kernel(const float* __restrict__ src, u16* __restrict__ dst){
  int wave = threadIdx.x >> 6, lane = threadIdx.x & 63;
  int tok = blockIdx.x*4 + wave;
  const float* p = src + (size_t)tok*256;
  f4 a = *(const f4*)(p + lane*4);
  float s = a[0]+a[1]+a[2]+a[3];
  float s2 = a[0]*a[0]+a[1]*a[1]+a[2]*a[2]+a[3]*a[3];
  s = wsum(s); s2 = wsum(s2);
  float mean = s*(1.f/256.f);
  float var  = s2*(1.f/256.f) - mean*mean;
  float rstd = rsqrtf(var + 1e-5f);
  us4 o;
  #pragma unroll
  for (int e=0;e<4;e++) o[e] = f2bf((a[e]-mean)*rstd);
  *(us4*)(dst + (size_t)tok*256 + lane*4) = o;
}

// ------------- fold LN affine into weights -------------
__global__ void prep_weights(
    const float* __restrict__ qkv_w, const float* __restrict__ qkv_b,
    const float* __restrict__ ln1w,  const float* __restrict__ ln1b,
    const float* __restrict__ fc1_w, const float* __restrict__ fc1_b,
    const float* __restrict__ ln2w,  const float* __restrict__ ln2b,
    const float* __restrict__ fc2_w, const float* __restrict__ fc2_b,
    const float* __restrict__ ln3w,  const float* __restrict__ ln3b,
    const float* __restrict__ proj_w, const float* __restrict__ proj_b,
    u16* __restrict__ wq, float* __restrict__ bq,
    u16* __restrict__ w1, float* __restrict__ b1,
    u16* __restrict__ w2, float* __restrict__ b2,
    u16* __restrict__ wp, float* __restrict__ bp)
{
  int wave = threadIdx.x>>6, lane = threadIdx.x&63;
  int n = blockIdx.x*4 + wave;
  const float *W,*lw,*lb,*bs; u16* WO; float* BO; int K, row, noln;
  if (n < 768)      { W=qkv_w; lw=ln1w; lb=ln1b; bs=qkv_b; WO=wq; BO=bq; K=256;  row=n;      noln=0; }
  else if (n < 1792){ W=fc1_w; lw=ln2w; lb=ln2b; bs=fc1_b; WO=w1; BO=b1; K=256;  row=n-768;  noln=0; }
  else if (n < 2048){ W=fc2_w; lw=ln3w; lb=ln3b; bs=fc2_b; WO=w2; BO=b2; K=1024; row=n-1792; noln=0; }
  else              { W=proj_w; lw=nullptr; lb=nullptr; bs=proj_b; WO=wp; BO=bp; K=256; row=n-2048; noln=1; }
  float dot = 0.f;
  for (int k=lane; k<K; k+=64){
    float wv = W[(size_t)row*K + k];
    if (noln){
      WO[(size_t)row*K + k] = f2bf(wv);
    } else {
      dot += wv * lb[k];
      WO[(size_t)row*K + k] = f2bf(wv * lw[k]);
    }
  }
  dot = wsum(dot);
  if (lane==0) BO[row] = bs[row] + dot;
}

// ---------------- GEMM v4: dbuf 2-phase + T2 swizzle ----------------
// SMODE: 0 = glds A, gathered rows (tok2pix), bf16
//        1 = glds A, linear rows, bf16
//        2 = reg-staged A + LN, bf16 (fc2)
//        3 = reg-staged A + LN, f32 (fc1 fallback)
// EPI:   0 = +bias, split q|k|v bf16 [3][pair][49][32]
//        1 = +bias + resid, scatter f32 via tok2pix  (vector f4 stores)
//        2 = +bias, GELU, bf16 h [row][1024]
//        3 = +bias + resid, f32 out [row][256]       (vector f4 stores)
template<int SMODE, int EPI>
__global__ __launch_bounds__(256)
void gemm4(const void* __restrict__ Av, const u16* __restrict__ Bt,
           const float* __restrict__ stats, const float* __restrict__ biasf,
           const float* __restrict__ resid, void* __restrict__ outv,
           int K, int NT, int CHUNK)
{
  constexpr int BM=128, BN=128, BK=64;
  __shared__ u16 smem[32768];                 // 64 KB: A dbuf 2x16KB | B dbuf 2x16KB
  // A buffers at u16-offset 0 / 8192; B buffers at 16384 / 24576 (computed, no ptr arrays)
  int b = blockIdx.x;
  int linear = (b & 7)*CHUNK + (b >> 3);
  int mt = linear / NT, nt = linear - mt*NT;
  int m0 = mt*BM, n0 = nt*BN;
  int tid  = threadIdx.x;
  int lane = tid & 63, wave = tid >> 6;
  int wr = wave >> 1, wc = wave & 1;
  int lc16 = lane & 15, g = lane >> 4;
  int nsteps = K >> 6;

  // staging sources (chunk c = tid + i*256 -> LDS byte c*16, source col pre-swizzled)
  const u16* asrc[4];
  const u16* bsrc[4];
  #pragma unroll
  for (int i=0;i<4;i++){
    int c = tid + i*256;
    int row = c >> 3, ch = (c & 7) ^ (row & 7);
    if (SMODE <= 1){
      int grow = (SMODE==0) ? tok2pix(m0+row) : (m0+row);
      asrc[i] = (const u16*)Av + (size_t)grow*K + ch*8;
    }
    bsrc[i] = Bt + (size_t)(n0+row)*K + ch*8;
  }
  // reg-staged A (SMODE 2/3): per-row LN constants (K-invariant)
  float smean[4], srstd[4];
  if (SMODE >= 2){
    #pragma unroll
    for (int i=0;i<4;i++){
      int grow = m0 + ((tid + i*256) >> 3);
      smean[i] = stats[2*grow]; srstd[i] = stats[2*grow+1];
    }
  }

  f32x4 acc[4][4];
  #pragma unroll
  for (int i=0;i<4;i++)
    #pragma unroll
    for (int j=0;j<4;j++){ acc[i][j][0]=0.f; acc[i][j][1]=0.f; acc[i][j][2]=0.f; acc[i][j][3]=0.f; }

  us8 rcur[4]; f4 rcurf[4][2];
  // ---- prologue: stage tile 0 into buffer 0 ----
  if (SMODE <= 1){
    #pragma unroll
    for (int i=0;i<4;i++) glds16(asrc[i], smem + i*2048 + wave*512);
  } else {
    #pragma unroll
    for (int i=0;i<4;i++){
      int c = tid + i*256; int row = c>>3, ch = c&7;
      if (SMODE==2) rcur[i] = *(const us8*)((const u16*)Av + (size_t)(m0+row)*K + ch*8);
      else {
        const float* ap = (const float*)Av + (size_t)(m0+row)*K + ch*8;
        rcurf[i][0] = *(const f4*)ap; rcurf[i][1] = *(const f4*)(ap+4);
      }
    }
  }
  #pragma unroll
  for (int i=0;i<4;i++) glds16(bsrc[i], smem + 16384 + i*2048 + wave*512);

  for (int t=0; t<nsteps; ++t){
    int cur = t & 1;
    int curoff = cur << 13;       // *8192
    int nxtoff = (cur^1) << 13;
    us8 rnext[4]; f4 rnextf[4][2];
    int kt1 = (t+1) << 6;
    if (t+1 < nsteps){
      if (SMODE <= 1){
        #pragma unroll
        for (int i=0;i<4;i++) glds16(asrc[i]+kt1, smem + nxtoff + i*2048 + wave*512);
      } else {
        #pragma unroll
        for (int i=0;i<4;i++){
          int c = tid + i*256; int row = c>>3, ch = c&7;
          if (SMODE==2) rnext[i] = *(const us8*)((const u16*)Av + (size_t)(m0+row)*K + kt1 + ch*8);
          else {
            const float* ap = (const float*)Av + (size_t)(m0+row)*K + kt1 + ch*8;
            rnextf[i][0] = *(const f4*)ap; rnextf[i][1] = *(const f4*)(ap+4);
          }
        }
      }
      #pragma unroll
      for (int i=0;i<4;i++) glds16(bsrc[i]+kt1, smem + 16384 + nxtoff + i*2048 + wave*512);
    }
    if (SMODE >= 2){
      // LN + swizzled ds_write of current A tile (regs loaded last iter)
      #pragma unroll
      for (int i=0;i<4;i++){
        int c = tid + i*256; int row = c>>3, ch = c&7;
        us8 o;
        #pragma unroll
        for (int e=0;e<8;e++){
          float fv = (SMODE==2) ? bf2f(rcur[i][e]) : rcurf[i][e>>2][e&3];
          o[e] = f2bf((fv - smean[i])*srstd[i]);
        }
        u32 byte = (u32)(row*128 + ch*16) ^ ((u32)(row&7)<<4);
        *(us8*)(smem + curoff + (byte>>1)) = o;
      }
      asm volatile("s_waitcnt lgkmcnt(0)" ::: "memory");
    }
    if (t+1 < nsteps) asm volatile("s_waitcnt vmcnt(8)" ::: "memory");
    else              asm volatile("s_waitcnt vmcnt(0)" ::: "memory");
    __builtin_amdgcn_s_barrier();
    asm volatile("" ::: "memory");
    __builtin_amdgcn_sched_barrier(0);
    const u16* Ap = smem + curoff;
    const u16* Bp = smem + 16384 + curoff;
    #pragma unroll
    for (int kk=0; kk<2; kk++){
      bf16x8 af[4], bfr[4];
      #pragma unroll
      for (int mi=0;mi<4;mi++){
        int r = wr*64 + mi*16 + lc16;
        u32 byte = (u32)(r*128 + kk*64 + g*16) ^ ((u32)(r&7)<<4);
        af[mi] = *(const bf16x8*)(Ap + (byte>>1));
      }
      #pragma unroll
      for (int ni=0;ni<4;ni++){
        int r = wc*64 + ni*16 + lc16;
        u32 byte = (u32)(r*128 + kk*64 + g*16) ^ ((u32)(r&7)<<4);
        bfr[ni] = *(const bf16x8*)(Bp + (byte>>1));
      }
      #pragma unroll
      for (int mi=0;mi<4;mi++)
        #pragma unroll
        for (int ni=0;ni<4;ni++)
          acc[mi][ni] = __builtin_amdgcn_mfma_f32_16x16x32_bf16(af[mi], bfr[ni], acc[mi][ni], 0, 0, 0);
    }
    asm volatile("" ::: "memory");
    __builtin_amdgcn_s_barrier();
    asm volatile("" ::: "memory");
    if (SMODE >= 2 && t+1 < nsteps){
      #pragma unroll
      for (int i=0;i<4;i++){
        if (SMODE==2) rcur[i] = rnext[i];
        else { rcurf[i][0] = rnextf[i][0]; rcurf[i][1] = rnextf[i][1]; }
      }
    }
  }

  int lr = lane >> 4;
  if (EPI==0 || EPI==2){
    u16* Cs = smem;                               // 128x128 bf16 = 32 KB
    #pragma unroll
    for (int mi=0;mi<4;mi++){
      #pragma unroll
      for (int ni=0;ni<4;ni++){
        int cl = wc*64 + ni*16 + lc16;
        float bv = biasf[n0 + cl];
        #pragma unroll
        for (int j=0;j<4;j++){
          int rl = wr*64 + mi*16 + lr*4 + j;
          float v = acc[mi][ni][j] + bv;
          if (EPI==2) v = 0.5f*v*(1.f + erff(v*0.70710678118654752f));
          u32 byte = (u32)(rl*256 + cl*2) ^ ((u32)(rl&7)<<4);
          Cs[byte>>1] = f2bf(v);
        }
      }
    }
    __syncthreads();
    #pragma unroll
    for (int i=0;i<8;i++){
      int c = tid + i*256;
      int rl = c>>4, c0 = (c&15)*8;
      u32 byte = (u32)(rl*256 + c0*2) ^ ((u32)(rl&7)<<4);
      us8 v = *(const us8*)(Cs + (byte>>1));
      int row = m0 + rl, col = n0 + c0;
      if (EPI==0){
        int which = col>>8, hh = (col>>5)&7, d0 = col&31;
        int bwi = row/49, t = row - bwi*49;
        *(us8*)((u16*)outv + ((size_t)which*NPAIR + bwi*8 + hh)*(WA*32) + t*32 + d0) = v;
      } else {
        *(us8*)((u16*)outv + (size_t)row*1024 + col) = v;
      }
    }
  } else {
    float* Cs = (float*)smem;                     // 128x128 f32 = 64 KB
    #pragma unroll
    for (int mi=0;mi<4;mi++){
      #pragma unroll
      for (int ni=0;ni<4;ni++){
        int cl = wc*64 + ni*16 + lc16;
        float bv = biasf[n0 + cl];
        #pragma unroll
        for (int j=0;j<4;j++){
          int rl = wr*64 + mi*16 + lr*4 + j;
          u32 byte = (u32)(rl*512 + cl*4) ^ ((u32)(rl&7)<<4);
          *(float*)((char*)Cs + byte) = acc[mi][ni][j] + bv;
        }
      }
    }
    __syncthreads();
    #pragma unroll
    for (int p=0;p<16;p++){
      int c = tid + p*256;                        // 4096 chunks: 128 rows x 32
      int row = c>>5, ch = c&31;
      u32 byte = (u32)(row*512 + ch*16) ^ ((u32)(row&7)<<4);
      f4 v = *(const f4*)((const char*)Cs + byte);
      int grow = m0 + row, col = n0 + ch*4;
      size_t addr;
      if (EPI==1) addr = (size_t)tok2pix(grow)*256 + col;
      else        addr = (size_t)grow*256 + col;
      f4 rr = *(const f4*)(resid + addr);
      v += rr;
      *(f4*)((float*)outv + addr) = v;
    }
  }
}

// ---------------- MFMA windowed attention ----------------
__global__ void attn_mfma_kernel(
    const u16* __restrict__ qkv,
    const float* __restrict__ rpb,
    const int* __restrict__ rel,
    const float* __restrict__ mask,
    u16* __restrict__ outb)
{
  __shared__ u16 Kls[4][64*32];
  __shared__ u16 Vt [4][32*64];
  __shared__ u16 Pls[4][64*64];
  int wave = threadIdx.x>>6, lane = threadIdx.x&63;
  int pair = blockIdx.x*4 + wave;
  int bw = pair>>3, h = pair&7, w = bw&63;
  int lc = lane&15, g = lane>>4;
  const u16* qg = qkv + (size_t)pair*(WA*32);
  const u16* kg = qg + (size_t)NPAIR*(WA*32);
  const u16* vg = qg + (size_t)2*NPAIR*(WA*32);
  u16* Kp = &Kls[wave][0];
  u16* Vp = &Vt[wave][0];
  u16* Pp = &Pls[wave][0];

  #pragma unroll
  for (int i=0;i<4;i++){
    int idx = i*64 + lane;
    int r = idx>>2, seg = idx&3;
    us8 kv, vv;
    if (r < WA){
      kv = *(const us8*)(kg + r*32 + seg*8);
      vv = *(const us8*)(vg + r*32 + seg*8);
    } else {
      #pragma unroll
      for (int e=0;e<8;e++){ kv[e]=0; vv[e]=0; }
    }
    *(us8*)(Kp + r*32 + seg*8) = kv;
    #pragma unroll
    for (int e=0;e<8;e++){
      int d = seg*8 + e;
      u32 byte = ((u32)(d*128 + r*2)) ^ ((u32)(d&7)<<4);
      Vp[byte>>1] = vv[e];
    }
  }

  bf16x8 qa[4];
  #pragma unroll
  for (int mi=0;mi<4;mi++){
    int r = mi*16 + lc;
    if (r < WA) qa[mi] = *(const bf16x8*)(qg + r*32 + g*8);
    else { bf16x8 z;
           #pragma unroll
           for (int e=0;e<8;e++) z[e]=0; qa[mi]=z; }
  }

  f32x4 acc[4][4];
  #pragma unroll
  for (int i=0;i<4;i++)
    #pragma unroll
    for (int j=0;j<4;j++){ acc[i][j][0]=0.f; acc[i][j][1]=0.f; acc[i][j][2]=0.f; acc[i][j][3]=0.f; }
  __syncthreads();
  #pragma unroll
  for (int ni=0;ni<4;ni++){
    bf16x8 kb = *(const bf16x8*)(Kp + (ni*16+lc)*32 + g*8);
    #pragma unroll
    for (int mi=0;mi<4;mi++)
      acc[mi][ni] = __builtin_amdgcn_mfma_f32_16x16x32_bf16(qa[mi], kb, acc[mi][ni], 0, 0, 0);
  }

  const float scale = 0.17677669529663689f;
  float rinv[4][4];
  #pragma unroll
  for (int mi=0;mi<4;mi++){
    #pragma unroll
    for (int jr=0;jr<4;jr++){
      int i = mi*16 + g*4 + jr;
      float sv[4];
      #pragma unroll
      for (int ni=0;ni<4;ni++){
        int j = ni*16 + lc;
        float s;
        if (i < WA && j < WA){
          s = acc[mi][ni][jr]*scale + rpb[rel[i*WA+j]*8 + h] + mask[((size_t)w*WA + i)*WA + j];
        } else s = -1e9f;
        sv[ni] = s;
      }
      float mx = fmaxf(fmaxf(sv[0],sv[1]), fmaxf(sv[2],sv[3]));
      #pragma unroll
      for (int off=1; off<16; off<<=1) mx = fmaxf(mx, __shfl_xor(mx, off, 64));
      float sum = 0.f;
      #pragma unroll
      for (int ni=0;ni<4;ni++){ sv[ni] = __expf(sv[ni]-mx); sum += sv[ni]; }
      #pragma unroll
      for (int off=1; off<16; off<<=1) sum += __shfl_xor(sum, off, 64);
      rinv[mi][jr] = 1.f/sum;
      #pragma unroll
      for (int ni=0;ni<4;ni++){
        int j = ni*16 + lc;
        u32 byte = ((u32)(i*128 + j*2)) ^ ((u32)(i&7)<<4);
        Pp[byte>>1] = f2bf(sv[ni]);
      }
    }
  }

  bf16x8 vb[2][2];
  #pragma unroll
  for (int kk=0;kk<2;kk++)
    #pragma unroll
    for (int ni=0;ni<2;ni++){
      int d = ni*16 + lc;
      u32 byte = ((u32)(d*128 + kk*64 + g*16)) ^ ((u32)(d&7)<<4);
      vb[kk][ni] = *(const bf16x8*)(Vp + (byte>>1));
    }
  f32x4 aco[4][2];
  #pragma unroll
  for (int i=0;i<4;i++)
    #pragma unroll
    for (int j=0;j<2;j++){ aco[i][j][0]=0.f; aco[i][j][1]=0.f; aco[i][j][2]=0.f; aco[i][j][3]=0.f; }
  #pragma unroll
  for (int mi=0;mi<4;mi++){
    int r = mi*16 + lc;
    #pragma unroll
    for (int kk=0;kk<2;kk++){
      u32 byte = ((u32)(r*128 + kk*64 + g*16)) ^ ((u32)(r&7)<<4);
      bf16x8 pa = *(const bf16x8*)(Pp + (byte>>1));
      #pragma unroll
      for (int ni=0;ni<2;ni++)
        aco[mi][ni] = __builtin_amdgcn_mfma_f32_16x16x32_bf16(pa, vb[kk][ni], aco[mi][ni], 0, 0, 0);
    }
  }

  u16* Op = Kp;
  #pragma unroll
  for (int mi=0;mi<4;mi++){
    #pragma unroll
    for (int jr=0;jr<4;jr++){
      int i = mi*16 + g*4 + jr;
      if (i < WA){
        float rv = rinv[mi][jr];
        #pragma unroll
        for (int ni=0;ni<2;ni++)
          Op[i*32 + ni*16 + lc] = f2bf(aco[mi][ni][jr]*rv);
      }
    }
  }
  __syncthreads();
  size_t obase = (size_t)(bw*WA)*256 + h*32;
  #pragma unroll
  for (int i=0;i<4;i++){
    int c = i*64 + lane;
    if (c < WA*4){
      int t = c>>2, seg = c&3;
      *(us8*)(outb + obase + (size_t)t*256 + seg*8) = *(const us8*)(Op + t*32 + seg*8);
    }
  }
}

extern "C" void kernel_launch(void* const* d_in, const int* in_sizes, int n_in,
                              void* d_out, int out_size, void* d_ws, size_t ws_size,
                              hipStream_t stream) {
  const float* x      = (const float*)d_in[0];
  const float* ln1w   = (const float*)d_in[1];
  const float* ln1b   = (const float*)d_in[2];
  const float* qkv_w  = (const float*)d_in[3];
  const float* qkv_b  = (const float*)d_in[4];
  const float* rpb    = (const float*)d_in[5];
  const float* proj_w = (const float*)d_in[6];
  const float* proj_b = (const float*)d_in[7];
  const float* ln2w   = (const float*)d_in[8];
  const float* ln2b   = (const float*)d_in[9];
  const float* fc1_w  = (const float*)d_in[10];
  const float* fc1_b  = (const float*)d_in[11];
  const float* ln3w   = (const float*)d_in[12];
  const float* ln3b   = (const float*)d_in[13];
  const float* fc2_w  = (const float*)d_in[14];
  const float* fc2_b  = (const float*)d_in[15];
  const float* amask  = (const float*)d_in[16];
  const int*   rel    = (const int*)d_in[17];
  float* out = (float*)d_out;

  char* ws = (char*)d_ws;
  float* statsC = (float*)(ws);                        // 802816
  float* statsB = (float*)(ws +  802816);              // 802816
  float* bq     = (float*)(ws + 1605632);
  float* b1     = (float*)(ws + 1608704);
  float* b2     = (float*)(ws + 1612800);
  float* bp     = (float*)(ws + 1613824);
  u16*   wq     = (u16*)  (ws + 1614848);
  u16*   w1     = (u16*)  (ws + 2008064);
  u16*   w2     = (u16*)  (ws + 2532352);
  u16*   wp     = (u16*)  (ws + 3056640);
  const size_t P0 = 3187712;
  u16*   qkvbuf = (u16*)(ws + P0);
  u16*   attno  = (u16*)(ws + P0 + 154140672);
  u16*   xb     = (u16*)(ws + P0 + 154140672);         // aliases attno slot
  u16*   hbuf   = (u16*)(ws + P0);                     // aliases qkv+attno
  u16*   x1b    = (u16*)(ws + P0 + 205520896);
  const int bigws = (ws_size >= (size_t)(P0 + 205520896ull + 51380224ull));

  prep_weights<<<576,256,0,stream>>>(qkv_w,qkv_b,ln1w,ln1b, fc1_w,fc1_b,ln2w,ln2b,
                                     fc2_w,fc2_b,ln3w,ln3b, proj_w,proj_b,
                                     wq,bq, w1,b1, w2,b2, wp,bp);
  ln_apply_kernel<<<NTOK/4,256,0,stream>>>(x, xb);
  gemm4<0,0><<<784*6,256,0,stream>>>(xb, wq, nullptr, bq, nullptr, qkvbuf, 256, 6, 588);
  attn_mfma_kernel<<<NPAIR/4,256,0,stream>>>(qkvbuf, rpb, rel, amask, attno);
  gemm4<1,1><<<784*2,256,0,stream>>>(attno, wp, nullptr, bp, x, out, 256, 2, 196);
  if (bigws){
    ln_apply_kernel<<<NTOK/4,256,0,stream>>>(out, x1b);
    gemm4<1,2><<<784*8,256,0,stream>>>(x1b, w1, nullptr, b1, nullptr, hbuf, 256, 8, 784);
  } else {
    ln_stats_kernel<256,0><<<NTOK/4,256,0,stream>>>(out, statsB);
    gemm4<3,2><<<784*8,256,0,stream>>>(out, w1, statsB, b1, nullptr, hbuf, 256, 8, 784);
  }
  ln_stats_kernel<1024,1><<<NTOK/4,256,0,stream>>>(hbuf, statsC);
  gemm4<2,3><<<784*2,256,0,stream>>>(hbuf, w2, statsC, b2, out, out, 1024, 2, 196);
}